// Round 6
// baseline (206.038 us; speedup 1.0000x reference)
//
#include <hip/hip_runtime.h>
#include <math.h>

#define NPIX 65536
#define NB   4
#define NK   6
#define TK   8
#define NBUK 48   // NK*TK
#define NROW 51   // 48 buckets + 3 dump rows for dedup
#define NCH  256
#define GSP  2    // plane split in k_accum
#define NSEL (NB*NK*TK)   // 192 selections
#define CCAP 65536        // per-(b,c) compacted list capacity

// ---------------- init: zero atomic targets ----------------
__global__ __launch_bounds__(64) void k_init(unsigned* m_arr, unsigned* Mbits) {
  int t = threadIdx.x;
  if (t < NB * NK) { m_arr[t] = 0u; Mbits[t] = 0u; }
}

// ---------------- A1: cert, argmax, per-class m/M, ballot-based compaction ----------------
__global__ __launch_bounds__(256) void k_cert(const float* __restrict__ preds,
    float* __restrict__ cert, unsigned char* __restrict__ argm,
    unsigned* __restrict__ m_arr, unsigned* __restrict__ Mbits,
    float* __restrict__ clist) {
  __shared__ unsigned s_max[NK];
  __shared__ unsigned s_seg[4][4][NK];      // [wave][j][class] counts
  __shared__ unsigned s_segbase[4][4][NK];  // exclusive offset within block
  __shared__ unsigned s_bbase[NK];          // global base for this block
  int tid = threadIdx.x;
  int w = tid >> 6, lane = tid & 63;
  if (tid < NK) s_max[tid] = 0u;
  __syncthreads();
  int i = blockIdx.x * 256 + tid;           // 4 pixels each; one batch per 64 blocks
  int n4 = i << 2;
  int b = n4 >> 16;
  int n = n4 & (NPIX - 1);
  const float* pb = preds + (size_t)b * NK * NPIX + n;
  float4 pv[NK];
  #pragma unroll
  for (int k = 0; k < NK; ++k) pv[k] = *(const float4*)(pb + (size_t)k * NPIX);
  float cv[4]; int cls[4]; unsigned av = 0;
  #pragma unroll
  for (int j = 0; j < 4; ++j) {
    float m1 = -INFINITY, m2 = -INFINITY; int arg = 0;
    #pragma unroll
    for (int k = 0; k < NK; ++k) {
      float v = (j == 0) ? pv[k].x : (j == 1) ? pv[k].y : (j == 2) ? pv[k].z : pv[k].w;
      if (v > m1) { m2 = m1; m1 = v; arg = k; }
      else if (v > m2) m2 = v;
    }
    cv[j] = m1 - m2;                        // >= 0
    cls[j] = arg;
    av |= ((unsigned)arg) << (8 * j);
    atomicMax(&s_max[arg], __float_as_uint(cv[j]));
  }
  *(float4*)(cert + (size_t)b * NPIX + n) = make_float4(cv[0], cv[1], cv[2], cv[3]);
  *(unsigned*)(argm + (size_t)b * NPIX + n) = av;
  unsigned long long lmask = ((unsigned long long)1 << lane) - 1ull;
  unsigned myoff[4];
  #pragma unroll
  for (int j = 0; j < 4; ++j) {
    #pragma unroll
    for (int c = 0; c < NK; ++c) {
      unsigned long long mk = __ballot(cls[j] == c);
      if (cls[j] == c) myoff[j] = (unsigned)__popcll(mk & lmask);
      if (lane == 0) s_seg[w][j][c] = (unsigned)__popcll(mk);
    }
  }
  __syncthreads();
  if (tid < NK) {                           // one thread per class: scan 16 segments
    unsigned run = 0;
    #pragma unroll
    for (int s = 0; s < 16; ++s) {
      unsigned v = s_seg[s >> 2][s & 3][tid];
      s_segbase[s >> 2][s & 3][tid] = run;
      run += v;
    }
    s_bbase[tid] = atomicAdd(&m_arr[b * NK + tid], run);
    atomicMax(&Mbits[b * NK + tid], s_max[tid]);
  }
  __syncthreads();
  #pragma unroll
  for (int j = 0; j < 4; ++j) {
    int c = cls[j];
    clist[(size_t)(b * NK + c) * CCAP + s_bbase[c] + s_segbase[w][j][c] + myoff[j]] = cv[j];
  }
}

// ---------------- A2: one block per (b,c,t); 4 radix passes over compacted list ----------
__global__ __launch_bounds__(256) void k_thresh(const float* __restrict__ clist,
    const unsigned* __restrict__ m_arr, float* __restrict__ thr) {
  int g = blockIdx.x;                       // 0..191
  int bc = g >> 3;
  int t = g & 7;
  int tid = threadIdx.x;
  __shared__ unsigned hist[256];
  __shared__ unsigned s_sel, s_rank;
  unsigned m = m_arr[bc];
  if (m == 0) { if (tid == 0) thr[g] = 0.f; return; }
  unsigned long long ks = ((unsigned long long)m * (unsigned)(t + 1)) / TK;
  unsigned rank = ks ? (unsigned)ks : 1u;   // 1-based rank of threshold
  const unsigned* lp = (const unsigned*)clist + (size_t)bc * CCAP;
  unsigned prefix = 0;
  for (int pass = 0; pass < 4; ++pass) {
    int shift = 24 - 8 * pass;
    hist[tid] = 0u;
    __syncthreads();
    for (unsigned idx = tid; idx < m; idx += 256) {
      unsigned u = lp[idx];
      if (pass == 0 || (u >> (shift + 8)) == prefix)
        atomicAdd(&hist[(u >> shift) & 255u], 1u);
    }
    __syncthreads();
    if (tid == 0) {
      unsigned cum = 0, rn = rank, sel = 0;
      for (int bin = 255; bin >= 0; --bin) {
        unsigned hh = hist[bin]; cum += hh;
        if (cum >= rank) { sel = (unsigned)bin; rn = rank - (cum - hh); break; }
      }
      s_sel = sel; s_rank = rn;
    }
    __syncthreads();
    prefix = (prefix << 8) | s_sel;
    rank = s_rank;
    __syncthreads();
  }
  if (tid == 0) thr[g] = __uint_as_float(prefix);
}

// ---------------- A3: per-pixel packed (e | bucket) ----------------
__global__ __launch_bounds__(256) void k_bucket(const float* __restrict__ cert,
    const unsigned char* __restrict__ argm, const unsigned* __restrict__ Mbits,
    const float* __restrict__ thr, unsigned* __restrict__ eb_out) {
  __shared__ float s_thr[NSEL];
  __shared__ float s_M[NB * NK];
  int tid = threadIdx.x;
  if (tid < NSEL) s_thr[tid] = thr[tid];
  if (tid < NB * NK) s_M[tid] = __uint_as_float(Mbits[tid]);
  __syncthreads();
  int i = blockIdx.x * 256 + tid;
  int n4 = i << 2;
  int b = n4 >> 16;
  int n = n4 & (NPIX - 1);
  float4 cv = *(const float4*)(cert + (size_t)b * NPIX + n);
  unsigned av = *(const unsigned*)(argm + (size_t)b * NPIX + n);
  unsigned evv[4];
  #pragma unroll
  for (int j = 0; j < 4; ++j) {
    int c = (av >> (8 * j)) & 255;
    float ce = (j == 0) ? cv.x : (j == 1) ? cv.y : (j == 2) ? cv.z : cv.w;
    float e = expf(ce - s_M[b * NK + c]);
    const float* tc = &s_thr[(b * NK + c) * TK];
    int tmin = TK - 1;                      // in-class pixel always has ce >= thr[TK-1]
    #pragma unroll
    for (int tt = TK - 2; tt >= 0; --tt) if (ce >= tc[tt]) tmin = tt;
    evv[j] = (__float_as_uint(e) & 0xFFFFFFC0u) | (unsigned)(c * TK + tmin);
  }
  uint4 ev; ev.x = evv[0]; ev.y = evv[1]; ev.z = evv[2]; ev.w = evv[3];
  *(uint4*)(eb_out + (size_t)b * NPIX + n) = ev;
}

// ---------------- B: pass over x; dedup'd grouped LDS RMW (one wait per 4 pixels) ------
// grid = NB*(NCH+1)*GSP; chz==NCH is the z-plane (x==1) for deterministic Z sums.
#define EVF(u) __uint_as_float((u) & 0xFFFFFFC0u)

__device__ __forceinline__ void proc_group(uint4 e, float4 xv, float* mycol) {
  unsigned b0 = e.x & 63u, b1 = e.y & 63u, b2 = e.z & 63u, b3 = e.w & 63u;
  float v0 = xv.x * EVF(e.x), v1 = xv.y * EVF(e.y);
  float v2 = xv.z * EVF(e.z), v3 = xv.w * EVF(e.w);
  // dedup: guarantee pairwise-distinct rows; duplicates merge + redirect to dump rows
  if (b1 == b0) { v0 += v1; v1 = 0.f; b1 = 48u; }
  if (b2 == b0) { v0 += v2; v2 = 0.f; b2 = 49u; }
  else if (b2 == b1) { v1 += v2; v2 = 0.f; b2 = 49u; }
  if (b3 == b0) { v0 += v3; v3 = 0.f; b3 = 50u; }
  else if (b3 == b1) { v1 += v3; v3 = 0.f; b3 = 50u; }
  else if (b3 == b2) { v2 += v3; v3 = 0.f; b3 = 50u; }
  // all reads precede all writes -> compiler batches 4 ds_reads behind one wait
  float r0 = mycol[b0 * 64], r1 = mycol[b1 * 64];
  float r2 = mycol[b2 * 64], r3 = mycol[b3 * 64];
  mycol[b0 * 64] = r0 + v0;
  mycol[b1 * 64] = r1 + v1;
  mycol[b2 * 64] = r2 + v2;
  mycol[b3 * 64] = r3 + v3;
}

__global__ __launch_bounds__(256) void k_accum(const float* __restrict__ x,
    const unsigned* __restrict__ eb, float* __restrict__ psum, float* __restrict__ zbuf) {
  __shared__ float acc[4 * NROW * 64];      // [wave][row][lane]; lane-owned column
  __shared__ float wpart[4 * NBUK];
  int tid = threadIdx.x;
  int w = tid >> 6, lane = tid & 63;
  float* mycol = acc + (size_t)w * NROW * 64 + lane;
  #pragma unroll
  for (int k = 0; k < NROW; ++k) mycol[k * 64] = 0.f;
  __syncthreads();
  int blk = blockIdx.x;
  int g = blk & (GSP - 1);
  int pc = blk / GSP;
  int b = pc / (NCH + 1);
  int chz = pc % (NCH + 1);
  bool isz = (chz == NCH);
  const uint4*  ep4 = (const uint4*)(eb + (size_t)b * NPIX + g * (NPIX / GSP));
  const float4* xp4 = (const float4*)(x + ((size_t)b * NCH + chz) * NPIX + g * (NPIX / GSP));
  const int NIT = NPIX / GSP / 2048;        // 16 iterations of 2048 pixels
  const float4 ones = make_float4(1.f, 1.f, 1.f, 1.f);
  uint4 ea0, eb0, ea1, eb1; float4 xa0, xb0, xa1, xb1;
  ea0 = ep4[tid];       eb0 = ep4[tid + 256];
  xa0 = isz ? ones : xp4[tid];
  xb0 = isz ? ones : xp4[tid + 256];
  #pragma unroll
  for (int it = 0; it < NIT; it += 2) {
    int base1 = (it + 1) * 512;
    ea1 = ep4[base1 + tid]; eb1 = ep4[base1 + tid + 256];
    xa1 = isz ? ones : xp4[base1 + tid];
    xb1 = isz ? ones : xp4[base1 + tid + 256];
    proc_group(ea0, xa0, mycol); proc_group(eb0, xb0, mycol);
    if (it + 2 < NIT) {
      int base2 = (it + 2) * 512;
      ea0 = ep4[base2 + tid]; eb0 = ep4[base2 + tid + 256];
      xa0 = isz ? ones : xp4[base2 + tid];
      xb0 = isz ? ones : xp4[base2 + tid + 256];
    }
    proc_group(ea1, xa1, mycol); proc_group(eb1, xb1, mycol);
  }
  __syncthreads();
  for (int k = 0; k < NBUK; ++k) {
    float v = mycol[k * 64];
    #pragma unroll
    for (int d = 1; d < 64; d <<= 1) v += __shfl_xor(v, d, 64);
    if (lane == 0) wpart[w * NBUK + k] = v;
  }
  __syncthreads();
  if (tid < NBUK) {
    float s = wpart[tid] + wpart[NBUK + tid] + wpart[2 * NBUK + tid] + wpart[3 * NBUK + tid];
    if (!isz) psum[(((size_t)g * NB + b) * NCH + chz) * NBUK + tid] = s;
    else      zbuf[((size_t)g * NB + b) * NBUK + tid] = s;
  }
}

// ---------------- F: prefix over t, branch on m, write fs + fg ----------------
__global__ __launch_bounds__(256) void k_final(const float* __restrict__ psum,
    const float* __restrict__ zbuf, const unsigned* __restrict__ m_arr,
    float* __restrict__ out) {
  int i = blockIdx.x * 256 + threadIdx.x;   // (b, ch)
  if (i >= NB * NCH) return;
  int b = i >> 8;
  int ch = i & 255;
  float* fs = out + (size_t)i * NBUK;
  float* fg = out + (size_t)NB * NCH * NBUK + (size_t)i * NK;
  float t5[TK];
  #pragma unroll
  for (int c = 0; c < NK; ++c) {
    unsigned m = m_arr[b * NK + c];
    float P = 0.f, Z = 0.f;
    float vals[TK];
    #pragma unroll
    for (int t = 0; t < TK; ++t) {
      #pragma unroll
      for (int g = 0; g < GSP; ++g) {
        P += psum[(((size_t)g * NB + b) * NCH + ch) * NBUK + c * TK + t];
        Z += zbuf[((size_t)g * NB + b) * NBUK + c * TK + t];
      }
      vals[t] = P / Z;
    }
    float tot = vals[TK - 1];
    #pragma unroll
    for (int t = 0; t < TK; ++t) {
      float v = (m == 0u) ? 0.f : ((m < (unsigned)TK) ? tot : vals[t]);
      fs[c * TK + t] = v;
      if (c == NK - 1) t5[t] = v;
    }
  }
  #pragma unroll
  for (int v = 0; v < NK; ++v) fg[v] = t5[2 + v];
}

extern "C" void kernel_launch(void* const* d_in, const int* in_sizes, int n_in,
                              void* d_out, int out_size, void* d_ws, size_t ws_size,
                              hipStream_t stream) {
  const float* x     = (const float*)d_in[0];   // [4,256,256,256]
  const float* preds = (const float*)d_in[1];   // [4,6,256,256]
  float* out = (float*)d_out;
  char* ws = (char*)d_ws;
  float*         cert  = (float*)(ws);                       // 1 MiB
  unsigned char* argm  = (unsigned char*)(ws + 0x100000);    // 256 KiB
  unsigned*      eb    = (unsigned*)(ws + 0x140000);         // 1 MiB
  float*         clist = (float*)(ws + 0x240000);            // 6 MiB (24 x 65536 f32)
  unsigned*      m_arr = (unsigned*)(ws + 0x840000);         // 24 u32
  unsigned*      Mbits = (unsigned*)(ws + 0x840100);         // 24 u32
  float*         thr   = (float*)(ws + 0x840200);            // 192 f32
  float*         psum  = (float*)(ws + 0x850000);            // 384 KiB (GSP=2)
  float*         zbuf  = (float*)(ws + 0x8D0000);            // 1.5 KiB

  k_init  <<<1, 64, 0, stream>>>(m_arr, Mbits);
  k_cert  <<<256, 256, 0, stream>>>(preds, cert, argm, m_arr, Mbits, clist);
  k_thresh<<<NSEL, 256, 0, stream>>>(clist, m_arr, thr);
  k_bucket<<<256, 256, 0, stream>>>(cert, argm, Mbits, thr, eb);
  k_accum <<<NB * (NCH + 1) * GSP, 256, 0, stream>>>(x, eb, psum, zbuf);
  k_final <<<4, 256, 0, stream>>>(psum, zbuf, m_arr, out);
}

// Round 7
// 182.668 us; speedup vs baseline: 1.1279x; 1.1279x over previous
//
#include <hip/hip_runtime.h>
#include <math.h>

#define NPIX 65536
#define NB   4
#define NK   6
#define TK   8
#define NBUK 48   // NK*TK
#define NCH  256
#define GSP  8    // plane split in k_accum
#define NSEL (NB*NK*TK)   // 192 selections
#define CCAP 65536        // per-(b,c) compacted list capacity

// ---------------- init: zero atomic targets + fill ones buffer ----------------
__global__ __launch_bounds__(256) void k_init(unsigned* m_arr, unsigned* Mbits,
                                              float* ones) {
  int i = blockIdx.x * 256 + threadIdx.x;   // grid 8 -> 2048 threads
  if (i < NB * NK) { m_arr[i] = 0u; Mbits[i] = 0u; }
  for (int j = i; j < NPIX; j += 2048) ones[j] = 1.f;
}

// ---------------- A1: cert, argmax, per-class m/M, ballot-based compaction ----------------
__global__ __launch_bounds__(256) void k_cert(const float* __restrict__ preds,
    float* __restrict__ cert, unsigned char* __restrict__ argm,
    unsigned* __restrict__ m_arr, unsigned* __restrict__ Mbits,
    float* __restrict__ clist) {
  __shared__ unsigned s_max[NK];
  __shared__ unsigned s_seg[4][4][NK];      // [wave][j][class] counts
  __shared__ unsigned s_segbase[4][4][NK];  // exclusive offset within block
  __shared__ unsigned s_bbase[NK];          // global base for this block
  int tid = threadIdx.x;
  int w = tid >> 6, lane = tid & 63;
  if (tid < NK) s_max[tid] = 0u;
  __syncthreads();
  int i = blockIdx.x * 256 + tid;           // 4 pixels each; one batch per 64 blocks
  int n4 = i << 2;
  int b = n4 >> 16;
  int n = n4 & (NPIX - 1);
  const float* pb = preds + (size_t)b * NK * NPIX + n;
  float4 pv[NK];
  #pragma unroll
  for (int k = 0; k < NK; ++k) pv[k] = *(const float4*)(pb + (size_t)k * NPIX);
  float cv[4]; int cls[4]; unsigned av = 0;
  #pragma unroll
  for (int j = 0; j < 4; ++j) {
    float m1 = -INFINITY, m2 = -INFINITY; int arg = 0;
    #pragma unroll
    for (int k = 0; k < NK; ++k) {
      float v = (j == 0) ? pv[k].x : (j == 1) ? pv[k].y : (j == 2) ? pv[k].z : pv[k].w;
      if (v > m1) { m2 = m1; m1 = v; arg = k; }
      else if (v > m2) m2 = v;
    }
    cv[j] = m1 - m2;                        // >= 0
    cls[j] = arg;
    av |= ((unsigned)arg) << (8 * j);
    atomicMax(&s_max[arg], __float_as_uint(cv[j]));
  }
  *(float4*)(cert + (size_t)b * NPIX + n) = make_float4(cv[0], cv[1], cv[2], cv[3]);
  *(unsigned*)(argm + (size_t)b * NPIX + n) = av;
  unsigned long long lmask = ((unsigned long long)1 << lane) - 1ull;
  unsigned myoff[4];
  #pragma unroll
  for (int j = 0; j < 4; ++j) {
    #pragma unroll
    for (int c = 0; c < NK; ++c) {
      unsigned long long mk = __ballot(cls[j] == c);
      if (cls[j] == c) myoff[j] = (unsigned)__popcll(mk & lmask);
      if (lane == 0) s_seg[w][j][c] = (unsigned)__popcll(mk);
    }
  }
  __syncthreads();
  if (tid < NK) {                           // one thread per class: scan 16 segments
    unsigned run = 0;
    #pragma unroll
    for (int s = 0; s < 16; ++s) {
      unsigned v = s_seg[s >> 2][s & 3][tid];
      s_segbase[s >> 2][s & 3][tid] = run;
      run += v;
    }
    s_bbase[tid] = atomicAdd(&m_arr[b * NK + tid], run);
    atomicMax(&Mbits[b * NK + tid], s_max[tid]);
  }
  __syncthreads();
  #pragma unroll
  for (int j = 0; j < 4; ++j) {
    int c = cls[j];
    clist[(size_t)(b * NK + c) * CCAP + s_bbase[c] + s_segbase[w][j][c] + myoff[j]] = cv[j];
  }
}

// ---------------- A2: one block per (b,c,t); 4 radix passes over compacted list ----------
__global__ __launch_bounds__(256) void k_thresh(const float* __restrict__ clist,
    const unsigned* __restrict__ m_arr, float* __restrict__ thr) {
  int g = blockIdx.x;                       // 0..191
  int bc = g >> 3;
  int t = g & 7;
  int tid = threadIdx.x;
  __shared__ unsigned hist[256];
  __shared__ unsigned s_sel, s_rank;
  unsigned m = m_arr[bc];
  if (m == 0) { if (tid == 0) thr[g] = 0.f; return; }
  unsigned long long ks = ((unsigned long long)m * (unsigned)(t + 1)) / TK;
  unsigned rank = ks ? (unsigned)ks : 1u;   // 1-based rank of threshold
  const unsigned* lp = (const unsigned*)clist + (size_t)bc * CCAP;
  unsigned prefix = 0;
  for (int pass = 0; pass < 4; ++pass) {
    int shift = 24 - 8 * pass;
    hist[tid] = 0u;
    __syncthreads();
    for (unsigned idx = tid; idx < m; idx += 256) {
      unsigned u = lp[idx];
      if (pass == 0 || (u >> (shift + 8)) == prefix)
        atomicAdd(&hist[(u >> shift) & 255u], 1u);
    }
    __syncthreads();
    if (tid == 0) {
      unsigned cum = 0, rn = rank, sel = 0;
      for (int bin = 255; bin >= 0; --bin) {
        unsigned hh = hist[bin]; cum += hh;
        if (cum >= rank) { sel = (unsigned)bin; rn = rank - (cum - hh); break; }
      }
      s_sel = sel; s_rank = rn;
    }
    __syncthreads();
    prefix = (prefix << 8) | s_sel;
    rank = s_rank;
    __syncthreads();
  }
  if (tid == 0) thr[g] = __uint_as_float(prefix);
}

// ---------------- A3: per-pixel packed (e | bucket) ----------------
__global__ __launch_bounds__(256) void k_bucket(const float* __restrict__ cert,
    const unsigned char* __restrict__ argm, const unsigned* __restrict__ Mbits,
    const float* __restrict__ thr, unsigned* __restrict__ eb_out) {
  __shared__ float s_thr[NSEL];
  __shared__ float s_M[NB * NK];
  int tid = threadIdx.x;
  if (tid < NSEL) s_thr[tid] = thr[tid];
  if (tid < NB * NK) s_M[tid] = __uint_as_float(Mbits[tid]);
  __syncthreads();
  int i = blockIdx.x * 256 + tid;
  int n4 = i << 2;
  int b = n4 >> 16;
  int n = n4 & (NPIX - 1);
  float4 cv = *(const float4*)(cert + (size_t)b * NPIX + n);
  unsigned av = *(const unsigned*)(argm + (size_t)b * NPIX + n);
  unsigned evv[4];
  #pragma unroll
  for (int j = 0; j < 4; ++j) {
    int c = (av >> (8 * j)) & 255;
    float ce = (j == 0) ? cv.x : (j == 1) ? cv.y : (j == 2) ? cv.z : cv.w;
    float e = expf(ce - s_M[b * NK + c]);
    const float* tc = &s_thr[(b * NK + c) * TK];
    int tmin = TK - 1;                      // in-class pixel always has ce >= thr[TK-1]
    #pragma unroll
    for (int tt = TK - 2; tt >= 0; --tt) if (ce >= tc[tt]) tmin = tt;
    evv[j] = (__float_as_uint(e) & 0xFFFFFFC0u) | (unsigned)(c * TK + tmin);
  }
  uint4 ev; ev.x = evv[0]; ev.y = evv[1]; ev.z = evv[2]; ev.w = evv[3];
  *(uint4*)(eb_out + (size_t)b * NPIX + n) = ev;
}

// ---------------- B: 1-wave blocks, 12.3KB LDS -> ~13 blocks/CU; branch-free ----------
// grid = NB*(NCH+1)*GSP; chz==NCH uses the ones buffer (deterministic Z sums).
#define PROC(ev, xv) do { \
    unsigned u_; \
    u_ = ev.x; mycol[(u_ & 63u) * 64] += xv.x * __uint_as_float(u_ & 0xFFFFFFC0u); \
    u_ = ev.y; mycol[(u_ & 63u) * 64] += xv.y * __uint_as_float(u_ & 0xFFFFFFC0u); \
    u_ = ev.z; mycol[(u_ & 63u) * 64] += xv.z * __uint_as_float(u_ & 0xFFFFFFC0u); \
    u_ = ev.w; mycol[(u_ & 63u) * 64] += xv.w * __uint_as_float(u_ & 0xFFFFFFC0u); \
  } while (0)

__global__ __launch_bounds__(64) void k_accum(const float* __restrict__ x,
    const unsigned* __restrict__ eb, const float* __restrict__ ones,
    float* __restrict__ psum, float* __restrict__ zbuf) {
  __shared__ float acc[NBUK * 64];          // [bucket][lane]; lane-owned column
  int lane = threadIdx.x;
  float* mycol = acc + lane;
  #pragma unroll
  for (int k = 0; k < NBUK; ++k) mycol[k * 64] = 0.f;
  int blk = blockIdx.x;
  int g = blk & (GSP - 1);
  int pc = blk >> 3;                        // GSP == 8
  int b = pc / (NCH + 1);
  int chz = pc % (NCH + 1);
  const int PPB = NPIX / GSP;               // 8192 pixels per block
  const uint4* ep4 = (const uint4*)(eb + (size_t)b * NPIX + g * PPB);
  const float* xbase = (chz == NCH) ? ones : (x + ((size_t)b * NCH + chz) * NPIX);
  const float4* xp4 = (const float4*)(xbase + g * PPB);
  const int NIT = PPB / 256;                // 32 groups of 4 pixels per thread
  // rotating 4-deep prefetch (depth 3), fully unrolled -> static indices
  uint4 ebuf[4]; float4 xbuf[4];
  #pragma unroll
  for (int p = 0; p < 3; ++p) {
    ebuf[p] = ep4[lane + p * 64];
    xbuf[p] = xp4[lane + p * 64];
  }
  #pragma unroll
  for (int it = 0; it < NIT; ++it) {
    if (it + 3 < NIT) {
      ebuf[(it + 3) & 3] = ep4[lane + (it + 3) * 64];
      xbuf[(it + 3) & 3] = xp4[lane + (it + 3) * 64];
    }
    PROC(ebuf[it & 3], xbuf[it & 3]);
  }
  // single-wave reduce: no barrier needed (lane-owned columns, in-wave LDS order)
  for (int k = 0; k < NBUK; ++k) {
    float v = mycol[k * 64];
    #pragma unroll
    for (int d = 1; d < 64; d <<= 1) v += __shfl_xor(v, d, 64);
    if (lane == 0) {
      if (chz < NCH) psum[(((size_t)g * NB + b) * NCH + chz) * NBUK + k] = v;
      else           zbuf[((size_t)g * NB + b) * NBUK + k] = v;
    }
  }
}

// ---------------- F: prefix over t, branch on m, write fs + fg ----------------
__global__ __launch_bounds__(256) void k_final(const float* __restrict__ psum,
    const float* __restrict__ zbuf, const unsigned* __restrict__ m_arr,
    float* __restrict__ out) {
  int i = blockIdx.x * 256 + threadIdx.x;   // (b, ch)
  if (i >= NB * NCH) return;
  int b = i >> 8;
  int ch = i & 255;
  float* fs = out + (size_t)i * NBUK;
  float* fg = out + (size_t)NB * NCH * NBUK + (size_t)i * NK;
  float t5[TK];
  #pragma unroll
  for (int c = 0; c < NK; ++c) {
    unsigned m = m_arr[b * NK + c];
    float P = 0.f, Z = 0.f;
    float vals[TK];
    #pragma unroll
    for (int t = 0; t < TK; ++t) {
      #pragma unroll
      for (int g = 0; g < GSP; ++g) {
        P += psum[(((size_t)g * NB + b) * NCH + ch) * NBUK + c * TK + t];
        Z += zbuf[((size_t)g * NB + b) * NBUK + c * TK + t];
      }
      vals[t] = P / Z;
    }
    float tot = vals[TK - 1];
    #pragma unroll
    for (int t = 0; t < TK; ++t) {
      float v = (m == 0u) ? 0.f : ((m < (unsigned)TK) ? tot : vals[t]);
      fs[c * TK + t] = v;
      if (c == NK - 1) t5[t] = v;
    }
  }
  #pragma unroll
  for (int v = 0; v < NK; ++v) fg[v] = t5[2 + v];
}

extern "C" void kernel_launch(void* const* d_in, const int* in_sizes, int n_in,
                              void* d_out, int out_size, void* d_ws, size_t ws_size,
                              hipStream_t stream) {
  const float* x     = (const float*)d_in[0];   // [4,256,256,256]
  const float* preds = (const float*)d_in[1];   // [4,6,256,256]
  float* out = (float*)d_out;
  char* ws = (char*)d_ws;
  float*         cert  = (float*)(ws);                       // 1 MiB
  unsigned char* argm  = (unsigned char*)(ws + 0x100000);    // 256 KiB
  unsigned*      eb    = (unsigned*)(ws + 0x140000);         // 1 MiB
  float*         clist = (float*)(ws + 0x240000);            // 6 MiB (24 x 65536 f32)
  unsigned*      m_arr = (unsigned*)(ws + 0x840000);         // 24 u32
  unsigned*      Mbits = (unsigned*)(ws + 0x840100);         // 24 u32
  float*         thr   = (float*)(ws + 0x840200);            // 192 f32
  float*         ones  = (float*)(ws + 0x850000);            // 256 KiB
  float*         psum  = (float*)(ws + 0x890000);            // 1.5 MiB (GSP=8)
  float*         zbuf  = (float*)(ws + 0xA10000);            // 6 KiB

  k_init  <<<8, 256, 0, stream>>>(m_arr, Mbits, ones);
  k_cert  <<<256, 256, 0, stream>>>(preds, cert, argm, m_arr, Mbits, clist);
  k_thresh<<<NSEL, 256, 0, stream>>>(clist, m_arr, thr);
  k_bucket<<<256, 256, 0, stream>>>(cert, argm, Mbits, thr, eb);
  k_accum <<<NB * (NCH + 1) * GSP, 64, 0, stream>>>(x, eb, ones, psum, zbuf);
  k_final <<<4, 256, 0, stream>>>(psum, zbuf, m_arr, out);
}

// Round 8
// 165.521 us; speedup vs baseline: 1.2448x; 1.1036x over previous
//
#include <hip/hip_runtime.h>
#include <math.h>

#define NPIX 65536
#define NB   4
#define NK   6
#define TK   8
#define NBUK 48   // NK*TK
#define NCH  256
#define KSP  64   // K-chunks per batch in k_gemm
#define KCHUNK (NPIX/KSP)   // 1024
#define NSEL (NB*NK*TK)     // 192 selections
#define CCAP 65536

typedef __attribute__((ext_vector_type(8))) short bf16x8;
typedef __attribute__((ext_vector_type(4))) float f32x4;

// ---------------- init: zero atomic targets ----------------
__global__ __launch_bounds__(64) void k_init(unsigned* m_arr, unsigned* Mbits) {
  int t = threadIdx.x;
  if (t < NB * NK) { m_arr[t] = 0u; Mbits[t] = 0u; }
}

// ---------------- A1: cert, argmax, per-class m/M, ballot-based compaction ----------------
__global__ __launch_bounds__(256) void k_cert(const float* __restrict__ preds,
    float* __restrict__ cert, unsigned char* __restrict__ argm,
    unsigned* __restrict__ m_arr, unsigned* __restrict__ Mbits,
    float* __restrict__ clist) {
  __shared__ unsigned s_max[NK];
  __shared__ unsigned s_seg[4][4][NK];
  __shared__ unsigned s_segbase[4][4][NK];
  __shared__ unsigned s_bbase[NK];
  int tid = threadIdx.x;
  int w = tid >> 6, lane = tid & 63;
  if (tid < NK) s_max[tid] = 0u;
  __syncthreads();
  int i = blockIdx.x * 256 + tid;
  int n4 = i << 2;
  int b = n4 >> 16;
  int n = n4 & (NPIX - 1);
  const float* pb = preds + (size_t)b * NK * NPIX + n;
  float4 pv[NK];
  #pragma unroll
  for (int k = 0; k < NK; ++k) pv[k] = *(const float4*)(pb + (size_t)k * NPIX);
  float cv[4]; int cls[4]; unsigned av = 0;
  #pragma unroll
  for (int j = 0; j < 4; ++j) {
    float m1 = -INFINITY, m2 = -INFINITY; int arg = 0;
    #pragma unroll
    for (int k = 0; k < NK; ++k) {
      float v = (j == 0) ? pv[k].x : (j == 1) ? pv[k].y : (j == 2) ? pv[k].z : pv[k].w;
      if (v > m1) { m2 = m1; m1 = v; arg = k; }
      else if (v > m2) m2 = v;
    }
    cv[j] = m1 - m2;                        // >= 0
    cls[j] = arg;
    av |= ((unsigned)arg) << (8 * j);
    atomicMax(&s_max[arg], __float_as_uint(cv[j]));
  }
  *(float4*)(cert + (size_t)b * NPIX + n) = make_float4(cv[0], cv[1], cv[2], cv[3]);
  *(unsigned*)(argm + (size_t)b * NPIX + n) = av;
  unsigned long long lmask = ((unsigned long long)1 << lane) - 1ull;
  unsigned myoff[4];
  #pragma unroll
  for (int j = 0; j < 4; ++j) {
    #pragma unroll
    for (int c = 0; c < NK; ++c) {
      unsigned long long mk = __ballot(cls[j] == c);
      if (cls[j] == c) myoff[j] = (unsigned)__popcll(mk & lmask);
      if (lane == 0) s_seg[w][j][c] = (unsigned)__popcll(mk);
    }
  }
  __syncthreads();
  if (tid < NK) {
    unsigned run = 0;
    #pragma unroll
    for (int s = 0; s < 16; ++s) {
      unsigned v = s_seg[s >> 2][s & 3][tid];
      s_segbase[s >> 2][s & 3][tid] = run;
      run += v;
    }
    s_bbase[tid] = atomicAdd(&m_arr[b * NK + tid], run);
    atomicMax(&Mbits[b * NK + tid], s_max[tid]);
  }
  __syncthreads();
  #pragma unroll
  for (int j = 0; j < 4; ++j) {
    int c = cls[j];
    clist[(size_t)(b * NK + c) * CCAP + s_bbase[c] + s_segbase[w][j][c] + myoff[j]] = cv[j];
  }
}

// ---------------- A2: one block per (b,c,t); 4 radix passes over compacted list ----------
__global__ __launch_bounds__(256) void k_thresh(const float* __restrict__ clist,
    const unsigned* __restrict__ m_arr, float* __restrict__ thr) {
  int g = blockIdx.x;
  int bc = g >> 3;
  int t = g & 7;
  int tid = threadIdx.x;
  __shared__ unsigned hist[256];
  __shared__ unsigned s_sel, s_rank;
  unsigned m = m_arr[bc];
  if (m == 0) { if (tid == 0) thr[g] = 0.f; return; }
  unsigned long long ks = ((unsigned long long)m * (unsigned)(t + 1)) / TK;
  unsigned rank = ks ? (unsigned)ks : 1u;
  const unsigned* lp = (const unsigned*)clist + (size_t)bc * CCAP;
  unsigned prefix = 0;
  for (int pass = 0; pass < 4; ++pass) {
    int shift = 24 - 8 * pass;
    hist[tid] = 0u;
    __syncthreads();
    for (unsigned idx = tid; idx < m; idx += 256) {
      unsigned u = lp[idx];
      if (pass == 0 || (u >> (shift + 8)) == prefix)
        atomicAdd(&hist[(u >> shift) & 255u], 1u);
    }
    __syncthreads();
    if (tid == 0) {
      unsigned cum = 0, rn = rank, sel = 0;
      for (int bin = 255; bin >= 0; --bin) {
        unsigned hh = hist[bin]; cum += hh;
        if (cum >= rank) { sel = (unsigned)bin; rn = rank - (cum - hh); break; }
      }
      s_sel = sel; s_rank = rn;
    }
    __syncthreads();
    prefix = (prefix << 8) | s_sel;
    rank = s_rank;
    __syncthreads();
  }
  if (tid == 0) thr[g] = __uint_as_float(prefix);
}

// ---------------- A3: packed (e | bucket) + deterministic Z partials ----------------
__global__ __launch_bounds__(256) void k_bucket(const float* __restrict__ cert,
    const unsigned char* __restrict__ argm, const unsigned* __restrict__ Mbits,
    const float* __restrict__ thr, unsigned* __restrict__ eb_out,
    float* __restrict__ zpart) {
  __shared__ float zacc[4 * NBUK * 64];     // [wave][bucket][lane]
  __shared__ float wpart[4 * NBUK];
  __shared__ float s_thr[NSEL];
  __shared__ float s_M[NB * NK];
  int tid = threadIdx.x;
  int w = tid >> 6, lane = tid & 63;
  float* mycol = zacc + (size_t)w * NBUK * 64 + lane;
  if (tid < NSEL) s_thr[tid] = thr[tid];
  if (tid < NB * NK) s_M[tid] = __uint_as_float(Mbits[tid]);
  #pragma unroll
  for (int k = 0; k < NBUK; ++k) mycol[k * 64] = 0.f;
  __syncthreads();
  int i = blockIdx.x * 256 + tid;
  int n4 = i << 2;
  int b = n4 >> 16;
  int n = n4 & (NPIX - 1);
  float4 cv = *(const float4*)(cert + (size_t)b * NPIX + n);
  unsigned av = *(const unsigned*)(argm + (size_t)b * NPIX + n);
  unsigned evv[4];
  #pragma unroll
  for (int j = 0; j < 4; ++j) {
    int c = (av >> (8 * j)) & 255;
    float ce = (j == 0) ? cv.x : (j == 1) ? cv.y : (j == 2) ? cv.z : cv.w;
    float e = expf(ce - s_M[b * NK + c]);
    const float* tc = &s_thr[(b * NK + c) * TK];
    int tmin = TK - 1;
    #pragma unroll
    for (int tt = TK - 2; tt >= 0; --tt) if (ce >= tc[tt]) tmin = tt;
    evv[j] = (__float_as_uint(e) & 0xFFFFFFC0u) | (unsigned)(c * TK + tmin);
    // Z from the SAME bf16-truncated e that k_gemm will use -> rounding cancels in P/Z
    mycol[(evv[j] & 63u) * 64] += __uint_as_float(evv[j] & 0xFFFF0000u);
  }
  uint4 ev; ev.x = evv[0]; ev.y = evv[1]; ev.z = evv[2]; ev.w = evv[3];
  *(uint4*)(eb_out + (size_t)b * NPIX + n) = ev;
  __syncthreads();
  for (int k = 0; k < NBUK; ++k) {
    float v = mycol[k * 64];
    #pragma unroll
    for (int d = 1; d < 64; d <<= 1) v += __shfl_xor(v, d, 64);
    if (lane == 0) wpart[w * NBUK + k] = v;
  }
  __syncthreads();
  if (tid < NBUK)
    zpart[(size_t)blockIdx.x * NBUK + tid] =
      wpart[tid] + wpart[NBUK + tid] + wpart[2 * NBUK + tid] + wpart[3 * NBUK + tid];
}

// ---------------- Zred: 64 block-partials per batch -> zfin[b][48] ----------------
__global__ __launch_bounds__(192) void k_zred(const float* __restrict__ zpart,
                                              float* __restrict__ zfin) {
  int t = threadIdx.x;                      // 0..191
  int b = t / NBUK, k = t % NBUK;
  float s = 0.f;
  for (int i = 0; i < 64; ++i) s += zpart[(size_t)(b * 64 + i) * NBUK + k];
  zfin[b * NBUK + k] = s;
}

// ---------------- B: MFMA GEMM  psum[b,ch,g,48] = E[48 x K] * X^T[K x 256] ----------
// E built in LDS per 512-pixel sub-chunk (one nonzero per column), reused by all 256 ch.
// x streamed coalesced f32, split hi+lo bf16 (2 MFMAs) -> no x-quantization error.
__global__ __launch_bounds__(512) void k_gemm(const float* __restrict__ x,
    const unsigned* __restrict__ eb, float* __restrict__ psum) {
  __shared__ short E[16 * 3 * 64 * 8];      // [ks][mtile][lane][8] bf16 = 48 KB
  int tid = threadIdx.x;
  int w = tid >> 6, lane = tid & 63;
  int bid = blockIdx.x;
  int b = bid >> 6;                         // KSP = 64
  int g = bid & 63;
  const unsigned* ebp = eb + (size_t)b * NPIX + g * KCHUNK;
  const float* xb = x + (size_t)b * NCH * NPIX;
  int q0ch = w * 32;                        // wave owns 32 channels
  f32x4 acc[3][2];
  #pragma unroll
  for (int m = 0; m < 3; ++m)
    #pragma unroll
    for (int q = 0; q < 2; ++q) acc[m][q] = (f32x4){0.f, 0.f, 0.f, 0.f};
  for (int sc = 0; sc < 2; ++sc) {
    __syncthreads();
    #pragma unroll
    for (int z = 0; z < 6; ++z)
      ((uint4*)E)[z * 512 + tid] = (uint4){0u, 0u, 0u, 0u};
    __syncthreads();
    {                                        // scatter 512 pixels, collision-free
      unsigned u = ebp[sc * 512 + tid];
      unsigned bk = u & 63u;
      int ks = tid >> 5, k = tid & 31;
      int el = (int)(bk & 15u) + ((k >> 3) << 4);
      E[((ks * 3 + (int)(bk >> 4)) * 64 + el) * 8 + (k & 7)] = (short)(u >> 16);
    }
    __syncthreads();
    int nbase = g * KCHUNK + sc * 512;
    for (int ks = 0; ks < 16; ++ks) {
      bf16x8 A0 = ((bf16x8*)E)[(ks * 3 + 0) * 64 + lane];
      bf16x8 A1 = ((bf16x8*)E)[(ks * 3 + 1) * 64 + lane];
      bf16x8 A2 = ((bf16x8*)E)[(ks * 3 + 2) * 64 + lane];
      #pragma unroll
      for (int q = 0; q < 2; ++q) {
        int ch = q0ch + q * 16 + (lane & 15);
        int n = nbase + ks * 32 + ((lane >> 4) << 3);
        const float* xp = xb + (size_t)ch * NPIX + n;
        float4 xa = *(const float4*)xp;
        float4 xv2 = *(const float4*)(xp + 4);
        float xv[8] = {xa.x, xa.y, xa.z, xa.w, xv2.x, xv2.y, xv2.z, xv2.w};
        bf16x8 Bh, Bl;
        #pragma unroll
        for (int j = 0; j < 8; ++j) {
          unsigned u = __float_as_uint(xv[j]);
          float hf = __uint_as_float(u & 0xFFFF0000u);   // truncated-bf16 hi
          float lo = xv[j] - hf;                          // exact residual
          Bh[j] = (short)(u >> 16);
          Bl[j] = (short)(__float_as_uint(lo) >> 16);     // truncated-bf16 lo
        }
        acc[0][q] = __builtin_amdgcn_mfma_f32_16x16x32_bf16(A0, Bh, acc[0][q], 0, 0, 0);
        acc[1][q] = __builtin_amdgcn_mfma_f32_16x16x32_bf16(A1, Bh, acc[1][q], 0, 0, 0);
        acc[2][q] = __builtin_amdgcn_mfma_f32_16x16x32_bf16(A2, Bh, acc[2][q], 0, 0, 0);
        acc[0][q] = __builtin_amdgcn_mfma_f32_16x16x32_bf16(A0, Bl, acc[0][q], 0, 0, 0);
        acc[1][q] = __builtin_amdgcn_mfma_f32_16x16x32_bf16(A1, Bl, acc[1][q], 0, 0, 0);
        acc[2][q] = __builtin_amdgcn_mfma_f32_16x16x32_bf16(A2, Bl, acc[2][q], 0, 0, 0);
      }
    }
  }
  // epilogue: C layout col=lane&15 (ch), row=(lane>>4)*4+i (bucket) [m89-verified]
  #pragma unroll
  for (int m = 0; m < 3; ++m)
    #pragma unroll
    for (int q = 0; q < 2; ++q)
      #pragma unroll
      for (int i = 0; i < 4; ++i) {
        int bucket = m * 16 + ((lane >> 4) << 2) + i;
        int ch = q0ch + q * 16 + (lane & 15);
        psum[((size_t)(b * NCH + ch) * KSP + g) * NBUK + bucket] = acc[m][q][i];
      }
}

// ---------------- F: reduce g-partials, prefix over t, branch on m, write fs+fg -------
__global__ __launch_bounds__(64) void k_final(const float* __restrict__ psum,
    const float* __restrict__ zfin, const unsigned* __restrict__ m_arr,
    float* __restrict__ out) {
  int bc_ = blockIdx.x;                     // (b*NCH + ch), 1024 blocks
  int lane = threadIdx.x;                   // g = lane
  int b = bc_ >> 8;
  const float* ps = psum + ((size_t)bc_ * KSP + lane) * NBUK;
  float p48[NBUK];
  #pragma unroll
  for (int i = 0; i < 12; ++i) {
    float4 v = ((const float4*)ps)[i];
    p48[4 * i] = v.x; p48[4 * i + 1] = v.y; p48[4 * i + 2] = v.z; p48[4 * i + 3] = v.w;
  }
  #pragma unroll
  for (int d = 1; d < 64; d <<= 1)
    #pragma unroll
    for (int k = 0; k < NBUK; ++k) p48[k] += __shfl_xor(p48[k], d, 64);
  if (lane == 0) {
    float* fs = out + (size_t)bc_ * NBUK;
    float* fg = out + (size_t)NB * NCH * NBUK + (size_t)bc_ * NK;
    float t5[TK];
    #pragma unroll
    for (int c = 0; c < NK; ++c) {
      unsigned m = m_arr[b * NK + c];
      float P = 0.f, Z = 0.f;
      float vals[TK];
      #pragma unroll
      for (int t = 0; t < TK; ++t) {
        P += p48[c * TK + t];
        Z += zfin[b * NBUK + c * TK + t];
        vals[t] = P / Z;
      }
      float tot = vals[TK - 1];
      #pragma unroll
      for (int t = 0; t < TK; ++t) {
        float v = (m == 0u) ? 0.f : ((m < (unsigned)TK) ? tot : vals[t]);
        fs[c * TK + t] = v;
        if (c == NK - 1) t5[t] = v;
      }
    }
    #pragma unroll
    for (int v = 0; v < NK; ++v) fg[v] = t5[2 + v];
  }
}

extern "C" void kernel_launch(void* const* d_in, const int* in_sizes, int n_in,
                              void* d_out, int out_size, void* d_ws, size_t ws_size,
                              hipStream_t stream) {
  const float* x     = (const float*)d_in[0];   // [4,256,256,256]
  const float* preds = (const float*)d_in[1];   // [4,6,256,256]
  float* out = (float*)d_out;
  char* ws = (char*)d_ws;
  float*         cert  = (float*)(ws);                       // 1 MiB
  unsigned char* argm  = (unsigned char*)(ws + 0x100000);    // 256 KiB
  unsigned*      eb    = (unsigned*)(ws + 0x140000);         // 1 MiB
  float*         clist = (float*)(ws + 0x240000);            // 6 MiB (union w/ psum)
  float*         psum  = (float*)(ws + 0x240000);            // 12.6 MiB (after k_thresh)
  unsigned*      m_arr = (unsigned*)(ws + 0xE40000);         // 24 u32
  unsigned*      Mbits = (unsigned*)(ws + 0xE40100);         // 24 u32
  float*         thr   = (float*)(ws + 0xE40200);            // 192 f32
  float*         zpart = (float*)(ws + 0xE41000);            // 48 KiB
  float*         zfin  = (float*)(ws + 0xE4E000);            // 768 B

  k_init  <<<1, 64, 0, stream>>>(m_arr, Mbits);
  k_cert  <<<256, 256, 0, stream>>>(preds, cert, argm, m_arr, Mbits, clist);
  k_thresh<<<NSEL, 256, 0, stream>>>(clist, m_arr, thr);
  k_bucket<<<256, 256, 0, stream>>>(cert, argm, Mbits, thr, eb, zpart);
  k_zred  <<<1, 192, 0, stream>>>(zpart, zfin);
  k_gemm  <<<NB * KSP, 512, 0, stream>>>(x, eb, psum);
  k_final <<<NB * NCH, 64, 0, stream>>>(psum, zfin, m_arr, out);
}